// Round 1
// baseline (304.388 us; speedup 1.0000x reference)
//
#include <hip/hip_runtime.h>
#include <hip/hip_bf16.h>

typedef __attribute__((ext_vector_type(8))) short short8;
typedef __attribute__((ext_vector_type(4))) float f32x4;
typedef __attribute__((ext_vector_type(8))) unsigned short ushort8;
typedef __attribute__((ext_vector_type(4))) unsigned short ushort4v;

__device__ __forceinline__ float bf2f(unsigned short u) {
  union { unsigned int i; float f; } v;
  v.i = ((unsigned int)u) << 16;
  return v.f;
}

__device__ __forceinline__ unsigned short f2bf(float f) {
  union { float f; unsigned int i; } v;
  v.f = f;
  unsigned int x = v.i;
  // round-to-nearest-even
  return (unsigned short)((x + 0x7FFFu + ((x >> 16) & 1u)) >> 16);
}

// ---------------------------------------------------------------------------
// Kernel 1: convert fc1w (f32) -> bf16, vectorized x4
// ---------------------------------------------------------------------------
__global__ __launch_bounds__(256) void cvt_bf16_kernel(
    const float* __restrict__ in, unsigned short* __restrict__ out, int n4) {
  int i = blockIdx.x * 256 + threadIdx.x;
  if (i >= n4) return;
  float4 v = ((const float4*)in)[i];
  ushort4v o;
  o[0] = f2bf(v.x); o[1] = f2bf(v.y); o[2] = f2bf(v.z); o[3] = f2bf(v.w);
  ((ushort4v*)out)[i] = o;
}

// ---------------------------------------------------------------------------
// Kernel 2: fused conv1 + conv2 -> out2 (bf16, layout [B][64*36] = [B][c2*36+p])
// Block = 256 threads, CONV_NB batch elements per block.
// ---------------------------------------------------------------------------
#define CONV_NB 16
__global__ __launch_bounds__(256) void conv_fused(
    const float* __restrict__ x, const float* __restrict__ w1,
    const float* __restrict__ w2, unsigned short* __restrict__ out2, int B) {
  __shared__ float s_o1[CONV_NB * 588];  // [bi][c][p], p = i*14+j
  __shared__ float s_w1[2352];           // [c][p][k], k = di*2+dj
  const int tid = threadIdx.x;
  const int b0 = blockIdx.x * CONV_NB;

  for (int i = tid; i < 2352; i += 256) s_w1[i] = w1[i];
  __syncthreads();

  // phase 1: out1[b,c,p] = relu(sum_k x_patch * w1)
  for (int i = tid; i < CONV_NB * 588; i += 256) {
    int bi = i / 588, cp = i % 588;
    int p = cp % 196;
    int pi = p / 14, pj = p % 14;
    const float* xb = x + (size_t)(b0 + bi) * 784;
    const float* wr = &s_w1[cp * 4];
    int base = 2 * pi * 28 + 2 * pj;
    float a = xb[base]          * wr[0] + xb[base + 1]      * wr[1]
            + xb[base + 28]     * wr[2] + xb[base + 29]     * wr[3];
    s_o1[i] = fmaxf(a, 0.0f);
  }
  __syncthreads();

  // phase 2: out2[b, c2, p] ; work item = (bi, p), loop c2 in regs
  for (int it = tid; it < CONV_NB * 36; it += 256) {
    int bi = it / 36, p = it % 36;
    int u = p / 6, u2 = p % 6;
    const float* o1b = &s_o1[bi * 588];
    float win[48];
    #pragma unroll
    for (int c = 0; c < 3; ++c)
      #pragma unroll
      for (int v = 0; v < 4; ++v) {
        const float* row = o1b + c * 196 + (2 * u + v) * 14 + 2 * u2;
        #pragma unroll
        for (int v2 = 0; v2 < 4; ++v2) win[c * 16 + v * 4 + v2] = row[v2];
      }
    unsigned short* dst = out2 + (size_t)(b0 + bi) * 2304 + p;
    const float* w2p = w2 + (size_t)p * 48;
    for (int c2 = 0; c2 < 64; ++c2) {
      const float* wr = w2p + (size_t)c2 * (36 * 48);
      float a = 0.f;
      #pragma unroll
      for (int k = 0; k < 48; ++k) a += win[k] * wr[k];
      dst[c2 * 36] = f2bf(fmaxf(a, 0.f));
    }
  }
}

// ---------------------------------------------------------------------------
// Kernel 3: h = relu(out2 @ fc1w^T)  -- M=8192, N=1024, K=2304, all bf16 in,
// f32 accum, bf16 out.  m97 structure: 128x128 tile, BK=32, 4 waves 2x2.
// ---------------------------------------------------------------------------
#define BM 128
#define BN 128
#define BK 32

__device__ __forceinline__ void async_load16(const void* g, void* l) {
  __builtin_amdgcn_global_load_lds(
      (const __attribute__((address_space(1))) unsigned int*)g,
      (__attribute__((address_space(3))) unsigned int*)l, 16, 0, 0);
}

__global__ __launch_bounds__(256) void gemm_fc1(
    const unsigned short* __restrict__ A,   // [M][K] out2 bf16
    const unsigned short* __restrict__ Bw,  // [N][K] fc1w bf16
    unsigned short* __restrict__ H,         // [M][N] bf16
    int M, int N, int K) {
  __shared__ unsigned short sA[BM * BK];  // row-major [128][32]
  __shared__ unsigned short sB[BN * BK];
  const int tid = threadIdx.x;
  const int lane = tid & 63;
  const int wave = tid >> 6;
  const int wr = wave >> 1, wc = wave & 1;
  const size_t m0 = (size_t)blockIdx.x * BM;  // row tile
  const size_t n0 = (size_t)blockIdx.y * BN;  // col tile
  f32x4 acc[4][4] = {};

  const int srow = tid >> 2;           // 0..63
  const int sk = (tid & 3) * 8;        // 0,8,16,24
  const unsigned short* Ab = A + (m0 + srow) * (size_t)K + sk;
  const unsigned short* Bb = Bw + (n0 + srow) * (size_t)K + sk;
  unsigned short* sAp = &sA[srow * BK + sk];
  unsigned short* sBp = &sB[srow * BK + sk];
  const int aoff = (lane & 15) * BK + (lane >> 4) * 8;  // fragment elem offset

  for (int k0 = 0; k0 < K; k0 += BK) {
    __syncthreads();
    async_load16(Ab + k0, sAp);
    async_load16(Ab + k0 + (size_t)64 * K, sAp + 64 * BK);
    async_load16(Bb + k0, sBp);
    async_load16(Bb + k0 + (size_t)64 * K, sBp + 64 * BK);
    __syncthreads();  // drains vmcnt(0): tile ready

    short8 af[4], bfr[4];
    #pragma unroll
    for (int m = 0; m < 4; ++m)
      af[m] = *(const short8*)&sA[(wr * 64 + m * 16) * BK + aoff];
    #pragma unroll
    for (int n = 0; n < 4; ++n)
      bfr[n] = *(const short8*)&sB[(wc * 64 + n * 16) * BK + aoff];
    #pragma unroll
    for (int m = 0; m < 4; ++m)
      #pragma unroll
      for (int n = 0; n < 4; ++n)
        acc[m][n] = __builtin_amdgcn_mfma_f32_16x16x32_bf16(af[m], bfr[n],
                                                            acc[m][n], 0, 0, 0);
  }

  // epilogue: relu + bf16 store. C layout: col=lane&15, row=(lane>>4)*4+j
  const int r0 = (int)m0 + wr * 64 + (lane >> 4) * 4;
  const int c0 = (int)n0 + wc * 64 + (lane & 15);
  #pragma unroll
  for (int m = 0; m < 4; ++m)
    #pragma unroll
    for (int n = 0; n < 4; ++n)
      #pragma unroll
      for (int j = 0; j < 4; ++j) {
        int r = r0 + m * 16 + j;
        int c = c0 + n * 16;
        H[(size_t)r * N + c] = f2bf(fmaxf(acc[m][n][j], 0.f));
      }
}

// ---------------------------------------------------------------------------
// Kernel 4: out = h @ fc2w^T  -- one wave per batch row, shfl reduction
// ---------------------------------------------------------------------------
__global__ __launch_bounds__(256) void fc2_kernel(
    const unsigned short* __restrict__ H, const float* __restrict__ W,
    float* __restrict__ out, int Bsz) {
  const int gw = (int)((blockIdx.x * 256 + threadIdx.x) >> 6);  // row
  const int lane = threadIdx.x & 63;
  if (gw >= Bsz) return;
  const ushort8* hp = (const ushort8*)(H + (size_t)gw * 1024 + lane * 16);
  ushort8 u0 = hp[0], u1 = hp[1];
  float hv[16];
  #pragma unroll
  for (int j = 0; j < 8; ++j) { hv[j] = bf2f(u0[j]); hv[8 + j] = bf2f(u1[j]); }
  float res[10];
  #pragma unroll
  for (int o = 0; o < 10; ++o) {
    const float4* wp = (const float4*)(W + o * 1024 + lane * 16);
    float a = 0.f;
    #pragma unroll
    for (int q = 0; q < 4; ++q) {
      float4 w4 = wp[q];
      a += hv[q * 4 + 0] * w4.x + hv[q * 4 + 1] * w4.y +
           hv[q * 4 + 2] * w4.z + hv[q * 4 + 3] * w4.w;
    }
    res[o] = a;
  }
  #pragma unroll
  for (int o = 0; o < 10; ++o) {
    float v = res[o];
    #pragma unroll
    for (int s = 32; s > 0; s >>= 1) v += __shfl_down(v, s);
    if (lane == 0) out[(size_t)gw * 10 + o] = v;
  }
}

// ---------------------------------------------------------------------------
extern "C" void kernel_launch(void* const* d_in, const int* in_sizes, int n_in,
                              void* d_out, int out_size, void* d_ws, size_t ws_size,
                              hipStream_t stream) {
  const float* x   = (const float*)d_in[0];
  const float* w1  = (const float*)d_in[1];
  const float* w2  = (const float*)d_in[2];
  const float* fc1 = (const float*)d_in[3];
  const float* fc2 = (const float*)d_in[4];
  float* out = (float*)d_out;
  const int B = in_sizes[0] / 784;  // 8192

  unsigned short* out2 = (unsigned short*)d_ws;          // B*2304 bf16
  unsigned short* fc1b = out2 + (size_t)B * 2304;        // 1024*2304 bf16
  unsigned short* h    = fc1b + (size_t)1024 * 2304;     // B*1024 bf16

  cvt_bf16_kernel<<<(1024 * 2304 / 4 + 255) / 256, 256, 0, stream>>>(
      fc1, fc1b, 1024 * 2304 / 4);
  conv_fused<<<B / CONV_NB, 256, 0, stream>>>(x, w1, w2, out2, B);
  dim3 g(B / BM, 1024 / BN);
  gemm_fc1<<<g, 256, 0, stream>>>(out2, fc1b, h, B, 1024, 2304);
  fc2_kernel<<<(B * 64 + 255) / 256, 256, 0, stream>>>(h, fc2, out, B);
}

// Round 2
// 136.401 us; speedup vs baseline: 2.2316x; 2.2316x over previous
//
#include <hip/hip_runtime.h>
#include <hip/hip_bf16.h>

typedef __attribute__((ext_vector_type(8))) short short8;
typedef __attribute__((ext_vector_type(4))) float f32x4;
typedef __attribute__((ext_vector_type(8))) unsigned short ushort8;
typedef __attribute__((ext_vector_type(4))) unsigned short ushort4v;

__device__ __forceinline__ float bf2f(unsigned short u) {
  union { unsigned int i; float f; } v;
  v.i = ((unsigned int)u) << 16;
  return v.f;
}

__device__ __forceinline__ unsigned short f2bf(float f) {
  union { float f; unsigned int i; } v;
  v.f = f;
  unsigned int x = v.i;
  return (unsigned short)((x + 0x7FFFu + ((x >> 16) & 1u)) >> 16);
}

// ---------------------------------------------------------------------------
// Kernel 1: fc1w f32 -> bf16 with k-permutation k' = p*64 + c2  (k = c2*36+p)
// One block per output row n; transpose via LDS.
// ---------------------------------------------------------------------------
__global__ __launch_bounds__(256) void cvt_permute(
    const float* __restrict__ fc1, unsigned short* __restrict__ out) {
  __shared__ float row[2304];
  const int n = blockIdx.x;
  const float* src = fc1 + (size_t)n * 2304;
  for (int i = threadIdx.x; i < 2304; i += 256) row[i] = src[i];
  __syncthreads();
  unsigned short* dst = out + (size_t)n * 2304;
  for (int i = threadIdx.x; i < 2304; i += 256) {
    int pp = i >> 6, c2 = i & 63;
    dst[i] = f2bf(row[c2 * 36 + pp]);
  }
}

// ---------------------------------------------------------------------------
// Kernel 2: fused conv1+conv2 as 36 x (B/64) micro-GEMMs via MFMA.
// Block = (64 batches, one p). out2 layout: [B][k'] with k' = p*64 + c2.
// ---------------------------------------------------------------------------
#define LDP 72  // LDS row stride in ushorts (144 B -> conflict-free-ish frags)
__global__ __launch_bounds__(256) void conv_fused2(
    const float* __restrict__ x, const float* __restrict__ w1,
    const float* __restrict__ w2, unsigned short* __restrict__ out2, int B) {
  __shared__ unsigned short s_w2[64 * LDP];   // [c2][k] bf16, k padded to 64
  __shared__ unsigned short s_win[64 * LDP];  // [bi][k] bf16, k padded to 64
  const int tid = threadIdx.x;
  const int b0 = blockIdx.x * 64;
  const int p = blockIdx.y;  // 0..35
  const int u = p / 6, u2 = p % 6;

  // phase 1: stage w2 slice [c2][48] -> bf16, zero-pad k 48..63
  const float* w2p = w2 + (size_t)p * 48;
  for (int i = tid; i < 64 * 64; i += 256) {
    int c2 = i >> 6, kk = i & 63;
    float v = (kk < 48) ? w2p[(size_t)c2 * 1728 + kk] : 0.f;
    s_w2[c2 * LDP + kk] = f2bf(v);
  }

  // phase 2: win[bi][kk] = conv1 window value (relu of 2x2 patch dot)
  for (int i = tid; i < 64 * 64; i += 256) {
    int bi = i >> 6, kk = i & 63;
    float a = 0.f;
    if (kk < 48) {
      int c = kk >> 4, rem = kk & 15, v = rem >> 2, v2 = rem & 3;
      int pi = 2 * u + v, pj = 2 * u2 + v2;
      const float* wr = w1 + (((c * 196) + pi * 14 + pj) << 2);
      const float* xb = x + (size_t)(b0 + bi) * 784 + pi * 56 + pj * 2;
      a = fmaxf(xb[0] * wr[0] + xb[1] * wr[1] + xb[28] * wr[2] + xb[29] * wr[3],
                0.f);
    }
    s_win[bi * LDP + kk] = f2bf(a);
  }
  __syncthreads();

  // phase 3: C[bi][c2] = win @ w2^T via 16x16x32 MFMA; waves tile 2x2 of 32x32
  const int lane = tid & 63, wave = tid >> 6;
  const int wm = wave >> 1, wn = wave & 1;
  const int fr = lane & 15, fo = (lane >> 4) * 8;
  f32x4 acc[2][2] = {};
  #pragma unroll
  for (int k2 = 0; k2 < 2; ++k2) {
    short8 af[2], bf[2];
    #pragma unroll
    for (int m = 0; m < 2; ++m)
      af[m] = *(const short8*)&s_win[(wm * 32 + m * 16 + fr) * LDP + k2 * 32 + fo];
    #pragma unroll
    for (int n = 0; n < 2; ++n)
      bf[n] = *(const short8*)&s_w2[(wn * 32 + n * 16 + fr) * LDP + k2 * 32 + fo];
    #pragma unroll
    for (int m = 0; m < 2; ++m)
      #pragma unroll
      for (int n = 0; n < 2; ++n)
        acc[m][n] =
            __builtin_amdgcn_mfma_f32_16x16x32_bf16(af[m], bf[n], acc[m][n], 0, 0, 0);
  }

  // epilogue: relu -> bf16, out2[(b0+bi)][p*64 + c2]
  const int r0 = wm * 32 + (lane >> 4) * 4;
  const int c0 = wn * 32 + fr;
  #pragma unroll
  for (int m = 0; m < 2; ++m)
    #pragma unroll
    for (int n = 0; n < 2; ++n)
      #pragma unroll
      for (int j = 0; j < 4; ++j) {
        int bi = r0 + m * 16 + j;
        int c2 = c0 + n * 16;
        out2[(size_t)(b0 + bi) * 2304 + p * 64 + c2] =
            f2bf(fmaxf(acc[m][n][j], 0.f));
      }
}

// ---------------------------------------------------------------------------
// Kernel 3: h = relu(out2 @ fc1b^T) -- M=8192, N=1024, K=2304 (k' order),
// bf16 in, f32 accum, bf16 out. m97 structure: 128x128 tile, BK=32, 4 waves.
// ---------------------------------------------------------------------------
#define BM 128
#define BN 128
#define BK 32

__device__ __forceinline__ void async_load16(const void* g, void* l) {
  __builtin_amdgcn_global_load_lds(
      (const __attribute__((address_space(1))) unsigned int*)g,
      (__attribute__((address_space(3))) unsigned int*)l, 16, 0, 0);
}

__global__ __launch_bounds__(256) void gemm_fc1(
    const unsigned short* __restrict__ A,   // [M][K] out2 bf16 (k' order)
    const unsigned short* __restrict__ Bw,  // [N][K] fc1b bf16 (k' order)
    unsigned short* __restrict__ H,         // [M][N] bf16
    int M, int N, int K) {
  __shared__ unsigned short sA[BM * BK];
  __shared__ unsigned short sB[BN * BK];
  const int tid = threadIdx.x;
  const int lane = tid & 63;
  const int wave = tid >> 6;
  const int wr = wave >> 1, wc = wave & 1;
  const size_t m0 = (size_t)blockIdx.x * BM;
  const size_t n0 = (size_t)blockIdx.y * BN;
  f32x4 acc[4][4] = {};

  const int srow = tid >> 2;
  const int sk = (tid & 3) * 8;
  const unsigned short* Ab = A + (m0 + srow) * (size_t)K + sk;
  const unsigned short* Bb = Bw + (n0 + srow) * (size_t)K + sk;
  unsigned short* sAp = &sA[srow * BK + sk];
  unsigned short* sBp = &sB[srow * BK + sk];
  const int aoff = (lane & 15) * BK + (lane >> 4) * 8;

  for (int k0 = 0; k0 < K; k0 += BK) {
    __syncthreads();
    async_load16(Ab + k0, sAp);
    async_load16(Ab + k0 + (size_t)64 * K, sAp + 64 * BK);
    async_load16(Bb + k0, sBp);
    async_load16(Bb + k0 + (size_t)64 * K, sBp + 64 * BK);
    __syncthreads();

    short8 af[4], bfr[4];
    #pragma unroll
    for (int m = 0; m < 4; ++m)
      af[m] = *(const short8*)&sA[(wr * 64 + m * 16) * BK + aoff];
    #pragma unroll
    for (int n = 0; n < 4; ++n)
      bfr[n] = *(const short8*)&sB[(wc * 64 + n * 16) * BK + aoff];
    #pragma unroll
    for (int m = 0; m < 4; ++m)
      #pragma unroll
      for (int n = 0; n < 4; ++n)
        acc[m][n] = __builtin_amdgcn_mfma_f32_16x16x32_bf16(af[m], bfr[n],
                                                            acc[m][n], 0, 0, 0);
  }

  const int r0 = (int)m0 + wr * 64 + (lane >> 4) * 4;
  const int c0 = (int)n0 + wc * 64 + (lane & 15);
  #pragma unroll
  for (int m = 0; m < 4; ++m)
    #pragma unroll
    for (int n = 0; n < 4; ++n)
      #pragma unroll
      for (int j = 0; j < 4; ++j) {
        int r = r0 + m * 16 + j;
        int c = c0 + n * 16;
        H[(size_t)r * N + c] = f2bf(fmaxf(acc[m][n][j], 0.f));
      }
}

// ---------------------------------------------------------------------------
// Kernel 4: out = h @ fc2w^T -- one wave per batch row, shfl reduction
// ---------------------------------------------------------------------------
__global__ __launch_bounds__(256) void fc2_kernel(
    const unsigned short* __restrict__ H, const float* __restrict__ W,
    float* __restrict__ out, int Bsz) {
  const int gw = (int)((blockIdx.x * 256 + threadIdx.x) >> 6);
  const int lane = threadIdx.x & 63;
  if (gw >= Bsz) return;
  const ushort8* hp = (const ushort8*)(H + (size_t)gw * 1024 + lane * 16);
  ushort8 u0 = hp[0], u1 = hp[1];
  float hv[16];
  #pragma unroll
  for (int j = 0; j < 8; ++j) { hv[j] = bf2f(u0[j]); hv[8 + j] = bf2f(u1[j]); }
  float res[10];
  #pragma unroll
  for (int o = 0; o < 10; ++o) {
    const float4* wp = (const float4*)(W + o * 1024 + lane * 16);
    float a = 0.f;
    #pragma unroll
    for (int q = 0; q < 4; ++q) {
      float4 w4 = wp[q];
      a += hv[q * 4 + 0] * w4.x + hv[q * 4 + 1] * w4.y +
           hv[q * 4 + 2] * w4.z + hv[q * 4 + 3] * w4.w;
    }
    res[o] = a;
  }
  #pragma unroll
  for (int o = 0; o < 10; ++o) {
    float v = res[o];
    #pragma unroll
    for (int s = 32; s > 0; s >>= 1) v += __shfl_down(v, s);
    if (lane == 0) out[(size_t)gw * 10 + o] = v;
  }
}

// ---------------------------------------------------------------------------
extern "C" void kernel_launch(void* const* d_in, const int* in_sizes, int n_in,
                              void* d_out, int out_size, void* d_ws, size_t ws_size,
                              hipStream_t stream) {
  const float* x   = (const float*)d_in[0];
  const float* w1  = (const float*)d_in[1];
  const float* w2  = (const float*)d_in[2];
  const float* fc1 = (const float*)d_in[3];
  const float* fc2 = (const float*)d_in[4];
  float* out = (float*)d_out;
  const int B = in_sizes[0] / 784;  // 8192

  unsigned short* out2 = (unsigned short*)d_ws;          // B*2304 bf16
  unsigned short* fc1b = out2 + (size_t)B * 2304;        // 1024*2304 bf16
  unsigned short* h    = fc1b + (size_t)1024 * 2304;     // B*1024 bf16

  cvt_permute<<<1024, 256, 0, stream>>>(fc1, fc1b);
  dim3 cg(B / 64, 36);
  conv_fused2<<<cg, 256, 0, stream>>>(x, w1, w2, out2, B);
  dim3 g(B / BM, 1024 / BN);
  gemm_fc1<<<g, 256, 0, stream>>>(out2, fc1b, h, B, 1024, 2304);
  fc2_kernel<<<(B * 64 + 255) / 256, 256, 0, stream>>>(h, fc2, out, B);
}